// Round 7
// baseline (634.858 us; speedup 1.0000x reference)
//
#include <hip/hip_runtime.h>
#include <hip/hip_fp16.h>

// VGAE: h = relu(GC(x,W1)); mean=GC2(h,W2); ls=GC2(h,W3);
// z = mean + noise*exp(ls); out = sigmoid(z @ z^T)
// GC(x,W) = (segsum((x*rsqrt(deg_out))[src] -> dst) * rsqrt(deg_in)) @ W + b
// Linearity reorderings: @W before aggregation for ALL layers (agg(h)@W = agg(h@W),
// row-scales commute). Layer-2/3 share one dense GEMM hw = h@[W2|W3]; the second
// aggregation fuses rs_in-scale + bias + reparameterization and writes Zh fp16.
// GEMMs on matrix cores via fp16 hi/lo split-compensation (err ~2^-22, fp32-grade);
// gemm2's A (h) is already fp16 -> 2-term only.
// Decoder exploits symmetry: upper-tri tile pairs only, sigmoid once, mirrored tile
// stored via plain f32x4 (fragment holds 4 consecutive rows of one column).

#define NN 10000
#define NE 320000
#define FD 512
#define H1 256
#define H2 128

typedef _Float16 half8 __attribute__((ext_vector_type(8)));
typedef _Float16 half4 __attribute__((ext_vector_type(4)));
typedef float f32x4 __attribute__((ext_vector_type(4)));

__global__ void k_zero3(int* __restrict__ a, int* __restrict__ b, int* __restrict__ c, int n) {
    int i = blockIdx.x * blockDim.x + threadIdx.x;
    if (i < n) { a[i] = 0; b[i] = 0; c[i] = 0; }
}

__global__ void k_count(const int* __restrict__ src, const int* __restrict__ dst,
                        int* __restrict__ co, int* __restrict__ ci) {
    int e = blockIdx.x * blockDim.x + threadIdx.x;
    if (e < NE) {
        atomicAdd(&co[src[e]], 1);
        atomicAdd(&ci[dst[e]], 1);
    }
}

// One block: exclusive scan of in-degrees -> row_ptr; rsqrt of clamped degrees.
__global__ __launch_bounds__(1024) void k_scan(const int* __restrict__ ci, const int* __restrict__ co,
                                               int* __restrict__ row_ptr,
                                               float* __restrict__ rs_in, float* __restrict__ rs_out) {
    __shared__ int sm[1024];
    int tid = threadIdx.x;
    const int CH = (NN + 1023) / 1024;  // 10
    int base = tid * CH;
    int local[CH];
    int s = 0;
    #pragma unroll
    for (int i = 0; i < CH; ++i) {
        int idx = base + i;
        local[i] = s;
        if (idx < NN) s += ci[idx];
    }
    sm[tid] = s;
    __syncthreads();
    for (int off = 1; off < 1024; off <<= 1) {
        int v = (tid >= off) ? sm[tid - off] : 0;
        __syncthreads();
        sm[tid] += v;
        __syncthreads();
    }
    int excl = sm[tid] - s;
    #pragma unroll
    for (int i = 0; i < CH; ++i) {
        int idx = base + i;
        if (idx < NN) row_ptr[idx] = excl + local[i];
    }
    if (tid == 1023) row_ptr[NN] = sm[1023];
    for (int i = tid; i < NN; i += 1024) {
        int a = ci[i], b = co[i];
        rs_in[i]  = rsqrtf((float)(a > 1 ? a : 1));
        rs_out[i] = rsqrtf((float)(b > 1 ? b : 1));
    }
}

__global__ void k_bucket(const int* __restrict__ src, const int* __restrict__ dst,
                         const int* __restrict__ row_ptr, int* __restrict__ cursor,
                         int* __restrict__ esrc) {
    int e = blockIdx.x * blockDim.x + threadIdx.x;
    if (e < NE) {
        int d = dst[e];
        int p = row_ptr[d] + atomicAdd(&cursor[d], 1);
        esrc[p] = src[e];
    }
}

// W1[512][256] -> W1T[256][512] hi/lo; [W2|W3][256][128]x2 -> WcT[256][256] hi/lo.
__global__ void k_castW(const float* __restrict__ W1, const float* __restrict__ W2,
                        const float* __restrict__ W3,
                        _Float16* __restrict__ W1Th, _Float16* __restrict__ W1Tl,
                        _Float16* __restrict__ WcTh, _Float16* __restrict__ WcTl) {
    int idx = blockIdx.x * blockDim.x + threadIdx.x;
    if (idx < FD * H1) {
        int k = idx >> 8, n = idx & 255;     // coalesced read over n
        float v = W1[idx];
        _Float16 h = (_Float16)v;
        W1Th[n * FD + k] = h;
        W1Tl[n * FD + k] = (_Float16)(v - (float)h);
    } else if (idx < FD * H1 + H1 * H1) {
        int j = idx - FD * H1;
        int k = j >> 8, n = j & 255;
        float v = (n < H2) ? W2[k * H2 + n] : W3[k * H2 + (n - H2)];
        _Float16 h = (_Float16)v;
        WcTh[n * H1 + k] = h;
        WcTl[n * H1 + k] = (_Float16)(v - (float)h);
    }
}

// y1[M][256] fp16 = (diag(rs_out) * features) @ W1T^T.  A fp32 split hi/lo in-register.
// BM=BN=64, BK=64, 256 threads = 4 waves 2x2, wave 32x32 via 2x2 16x16x32 frags.
// 3-term compensation: AhBh + AhBl + AlBh.
__global__ __launch_bounds__(256) void k_gemm1(
    const float* __restrict__ A, const float* __restrict__ ascale,
    const _Float16* __restrict__ BTh, const _Float16* __restrict__ BTl,
    _Float16* __restrict__ C, int M) {
    const int K = FD;
    __shared__ __align__(16) _Float16 Ahs[64][72];
    __shared__ __align__(16) _Float16 Als[64][72];
    __shared__ __align__(16) _Float16 Bhs[64][72];
    __shared__ __align__(16) _Float16 Bls[64][72];
    int tid = threadIdx.x;
    int lane = tid & 63;
    int w = tid >> 6;
    int wr = (w >> 1) * 32, wc = (w & 1) * 32;
    int bm = blockIdx.x * 64, bn = blockIdx.y * 64;
    f32x4 acc[2][2] = {};
    for (int k0 = 0; k0 < K; k0 += 64) {
        __syncthreads();
        #pragma unroll
        for (int i = 0; i < 4; ++i) {
            int lin = i * 256 + tid;
            int r = lin >> 4, c = lin & 15;
            int gr = bm + r;
            float4 v = {0.f, 0.f, 0.f, 0.f};
            float s = 1.0f;
            if (gr < M) {
                v = *(const float4*)(A + (size_t)gr * K + k0 + c * 4);
                s = ascale[gr];
            }
            v.x *= s; v.y *= s; v.z *= s; v.w *= s;
            half4 hh = { (_Float16)v.x, (_Float16)v.y, (_Float16)v.z, (_Float16)v.w };
            half4 ll = { (_Float16)(v.x - (float)hh[0]), (_Float16)(v.y - (float)hh[1]),
                         (_Float16)(v.z - (float)hh[2]), (_Float16)(v.w - (float)hh[3]) };
            *(half4*)&Ahs[r][c * 4] = hh;
            *(half4*)&Als[r][c * 4] = ll;
        }
        #pragma unroll
        for (int i = 0; i < 2; ++i) {
            int lin = i * 256 + tid;
            int r = lin >> 3, c = lin & 7;
            *(int4*)&Bhs[r][c * 8] = *(const int4*)(BTh + (size_t)(bn + r) * K + k0 + c * 8);
            *(int4*)&Bls[r][c * 8] = *(const int4*)(BTl + (size_t)(bn + r) * K + k0 + c * 8);
        }
        __syncthreads();
        #pragma unroll
        for (int ks = 0; ks < 2; ++ks) {
            int kof = ks * 32 + ((lane >> 4) << 3);
            half8 ah[2], al[2], bh[2], bl[2];
            #pragma unroll
            for (int f = 0; f < 2; ++f) {
                ah[f] = *(const half8*)&Ahs[wr + f * 16 + (lane & 15)][kof];
                al[f] = *(const half8*)&Als[wr + f * 16 + (lane & 15)][kof];
                bh[f] = *(const half8*)&Bhs[wc + f * 16 + (lane & 15)][kof];
                bl[f] = *(const half8*)&Bls[wc + f * 16 + (lane & 15)][kof];
            }
            #pragma unroll
            for (int i = 0; i < 2; ++i)
                #pragma unroll
                for (int j = 0; j < 2; ++j) {
                    acc[i][j] = __builtin_amdgcn_mfma_f32_16x16x32_f16(ah[i], bh[j], acc[i][j], 0, 0, 0);
                    acc[i][j] = __builtin_amdgcn_mfma_f32_16x16x32_f16(ah[i], bl[j], acc[i][j], 0, 0, 0);
                    acc[i][j] = __builtin_amdgcn_mfma_f32_16x16x32_f16(al[i], bh[j], acc[i][j], 0, 0, 0);
                }
        }
    }
    int quad = lane >> 4, c16 = lane & 15;
    #pragma unroll
    for (int i = 0; i < 2; ++i) {
        int row0 = bm + wr + i * 16 + quad * 4;
        #pragma unroll
        for (int j = 0; j < 2; ++j) {
            int col = bn + wc + j * 16 + c16;
            #pragma unroll
            for (int r = 0; r < 4; ++r) {
                int row = row0 + r;
                if (row < M) C[(size_t)row * H1 + col] = (_Float16)acc[i][j][r];
            }
        }
    }
}

// hw[M][256] fp16 = h(fp16) @ WcT^T. A exactly fp16 -> 2-term compensation (AhBh+AhBl).
__global__ __launch_bounds__(256) void k_gemm2(
    const _Float16* __restrict__ A,
    const _Float16* __restrict__ BTh, const _Float16* __restrict__ BTl,
    _Float16* __restrict__ C, int M) {
    const int K = H1;
    __shared__ __align__(16) _Float16 Ahs[64][72];
    __shared__ __align__(16) _Float16 Bhs[64][72];
    __shared__ __align__(16) _Float16 Bls[64][72];
    int tid = threadIdx.x;
    int lane = tid & 63;
    int w = tid >> 6;
    int wr = (w >> 1) * 32, wc = (w & 1) * 32;
    int bm = blockIdx.x * 64, bn = blockIdx.y * 64;
    f32x4 acc[2][2] = {};
    for (int k0 = 0; k0 < K; k0 += 64) {
        __syncthreads();
        #pragma unroll
        for (int i = 0; i < 2; ++i) {
            int lin = i * 256 + tid;
            int r = lin >> 3, c = lin & 7;
            int gr = bm + r;
            int4 va = {0, 0, 0, 0};
            if (gr < M) va = *(const int4*)(A + (size_t)gr * K + k0 + c * 8);
            *(int4*)&Ahs[r][c * 8] = va;
            *(int4*)&Bhs[r][c * 8] = *(const int4*)(BTh + (size_t)(bn + r) * K + k0 + c * 8);
            *(int4*)&Bls[r][c * 8] = *(const int4*)(BTl + (size_t)(bn + r) * K + k0 + c * 8);
        }
        __syncthreads();
        #pragma unroll
        for (int ks = 0; ks < 2; ++ks) {
            int kof = ks * 32 + ((lane >> 4) << 3);
            half8 ah[2], bh[2], bl[2];
            #pragma unroll
            for (int f = 0; f < 2; ++f) {
                ah[f] = *(const half8*)&Ahs[wr + f * 16 + (lane & 15)][kof];
                bh[f] = *(const half8*)&Bhs[wc + f * 16 + (lane & 15)][kof];
                bl[f] = *(const half8*)&Bls[wc + f * 16 + (lane & 15)][kof];
            }
            #pragma unroll
            for (int i = 0; i < 2; ++i)
                #pragma unroll
                for (int j = 0; j < 2; ++j) {
                    acc[i][j] = __builtin_amdgcn_mfma_f32_16x16x32_f16(ah[i], bh[j], acc[i][j], 0, 0, 0);
                    acc[i][j] = __builtin_amdgcn_mfma_f32_16x16x32_f16(ah[i], bl[j], acc[i][j], 0, 0, 0);
                }
        }
    }
    int quad = lane >> 4, c16 = lane & 15;
    #pragma unroll
    for (int i = 0; i < 2; ++i) {
        int row0 = bm + wr + i * 16 + quad * 4;
        #pragma unroll
        for (int j = 0; j < 2; ++j) {
            int col = bn + wc + j * 16 + c16;
            #pragma unroll
            for (int r = 0; r < 4; ++r) {
                int row = row0 + r;
                if (row < M) C[(size_t)row * H1 + col] = (_Float16)acc[i][j][r];
            }
        }
    }
}

// Aggregation, one wave per node; 32 lanes x half8 (16B) per row, two edge slots
// (lane>>5) per step, 4-deep unroll -> 8 gathers in flight. Sub-halves combined
// via __shfl_xor(32).
// FIRST:  h = relu(agg(y1)*rs_in + b1) * rs_out -> fp16 [NN][256]
// !FIRST: gather hw; mean|ls = agg(hw)*rs_in + b2|b3; Zh = mean + noise*exp(ls)
//         (mean cols 0..127 on lanes cl<16, ls cols 128..255 fetched via shfl_xor(16))
template <bool FIRST>
__global__ __launch_bounds__(256) void k_agg(const _Float16* __restrict__ in,
                                             _Float16* __restrict__ outh,
                                             const int* __restrict__ esrc, const int* __restrict__ row_ptr,
                                             const float* __restrict__ rs_in, const float* __restrict__ rs_out,
                                             const float* __restrict__ b1,
                                             const float* __restrict__ b2, const float* __restrict__ b3,
                                             const float* __restrict__ noise) {
    int wid = (blockIdx.x * blockDim.x + threadIdx.x) >> 6;
    int lane = threadIdx.x & 63;
    if (wid >= NN) return;
    int sub = lane >> 5, cl = lane & 31;
    int beg = row_ptr[wid], end = row_ptr[wid + 1];
    float a[8] = {};
    const _Float16* basep = in + cl * 8;
    int e = beg + sub;
    for (; e + 6 < end; e += 8) {
        int s0 = esrc[e], s1 = esrc[e + 2], s2 = esrc[e + 4], s3 = esrc[e + 6];
        half8 v0 = *(const half8*)(basep + (size_t)s0 * H1);
        half8 v1 = *(const half8*)(basep + (size_t)s1 * H1);
        half8 v2 = *(const half8*)(basep + (size_t)s2 * H1);
        half8 v3 = *(const half8*)(basep + (size_t)s3 * H1);
        #pragma unroll
        for (int j = 0; j < 8; ++j)
            a[j] += ((float)v0[j] + (float)v1[j]) + ((float)v2[j] + (float)v3[j]);
    }
    for (; e < end; e += 2) {
        half8 v = *(const half8*)(basep + (size_t)esrc[e] * H1);
        #pragma unroll
        for (int j = 0; j < 8; ++j) a[j] += (float)v[j];
    }
    #pragma unroll
    for (int j = 0; j < 8; ++j) a[j] += __shfl_xor(a[j], 32);
    float si = rs_in[wid];
    if (FIRST) {
        if (sub == 0) {
            float so = rs_out[wid];
            float4 bb0 = *(const float4*)(b1 + cl * 8);
            float4 bb1 = *(const float4*)(b1 + cl * 8 + 4);
            float bb[8] = {bb0.x, bb0.y, bb0.z, bb0.w, bb1.x, bb1.y, bb1.z, bb1.w};
            half8 hh;
            #pragma unroll
            for (int j = 0; j < 8; ++j)
                hh[j] = (_Float16)(fmaxf(a[j] * si + bb[j], 0.f) * so);
            *(half8*)(outh + (size_t)wid * H1 + cl * 8) = hh;
        }
    } else {
        float ls[8];
        #pragma unroll
        for (int j = 0; j < 8; ++j) ls[j] = __shfl_xor(a[j], 16);
        if (sub == 0 && cl < 16) {
            int c0 = cl * 8;
            float4 m0 = *(const float4*)(b2 + c0);
            float4 m1 = *(const float4*)(b2 + c0 + 4);
            float4 l0 = *(const float4*)(b3 + c0);
            float4 l1 = *(const float4*)(b3 + c0 + 4);
            float bm_[8] = {m0.x, m0.y, m0.z, m0.w, m1.x, m1.y, m1.z, m1.w};
            float bl_[8] = {l0.x, l0.y, l0.z, l0.w, l1.x, l1.y, l1.z, l1.w};
            float4 n0 = *(const float4*)(noise + (size_t)wid * H2 + c0);
            float4 n1 = *(const float4*)(noise + (size_t)wid * H2 + c0 + 4);
            float nn_[8] = {n0.x, n0.y, n0.z, n0.w, n1.x, n1.y, n1.z, n1.w};
            half8 zz;
            #pragma unroll
            for (int j = 0; j < 8; ++j) {
                float mean = a[j] * si + bm_[j];
                float lsv  = ls[j] * si + bl_[j];
                zz[j] = (_Float16)(mean + nn_[j] * __expf(lsv));
            }
            *(half8*)(outh + (size_t)wid * H2 + c0) = zz;
        }
    }
}

// out = sigmoid(Z @ Z^T), symmetric: one block per upper-tri tile pair (bi<=bj),
// 128x128 tile, 4 waves of 64x64, K=128 staged 2x64 in LDS. Sigmoid computed once;
// direct store scattered nontemporal dwords, mirror store (bi!=bj) as plain f32x4
// (fragment holds 4 consecutive rows of one column -> contiguous at out[col*NN+row0]).
__global__ __launch_bounds__(256) void k_decoder(const _Float16* __restrict__ Z, float* __restrict__ out) {
    const int NB = (NN + 127) / 128;  // 79
    __shared__ __align__(16) _Float16 As[128][72];
    __shared__ __align__(16) _Float16 Bs[128][72];
    // Integer-only decode t -> (bi,bj), bi<=bj. start(b) = b*NB - b*(b-1)/2.
    int t = blockIdx.x;
    int bi = 0;
    int startNext = NB;  // start(1)
    while (startNext <= t) {
        ++bi;
        startNext += NB - bi;  // start(bi+1) = start(bi) + (NB - bi)
    }
    int startBi = startNext - (NB - bi);
    int bj = bi + (t - startBi);
    int rowBase = bi * 128;
    int colBase = bj * 128;
    bool diag = (bi == bj);
    int tid = threadIdx.x;
    int lane = tid & 63;
    int w = tid >> 6;
    int wrow = (w >> 1) * 64;
    int wcol = (w & 1) * 64;
    f32x4 acc[4][4] = {};
    for (int s = 0; s < 2; ++s) {
        __syncthreads();
        #pragma unroll
        for (int i = 0; i < 4; ++i) {
            int lin = i * 256 + tid;
            int r = lin >> 3, c = lin & 7;
            int4 v = {0, 0, 0, 0};
            int gr = rowBase + r;
            if (gr < NN) v = *(const int4*)(Z + (size_t)gr * H2 + s * 64 + c * 8);
            *(int4*)&As[r][c * 8] = v;
            int4 u = {0, 0, 0, 0};
            int gc = colBase + r;
            if (gc < NN) u = *(const int4*)(Z + (size_t)gc * H2 + s * 64 + c * 8);
            *(int4*)&Bs[r][c * 8] = u;
        }
        __syncthreads();
        #pragma unroll
        for (int kk = 0; kk < 2; ++kk) {
            int kof = kk * 32 + ((lane >> 4) << 3);
            half8 a[4], b[4];
            #pragma unroll
            for (int f = 0; f < 4; ++f) a[f] = *(const half8*)&As[wrow + f * 16 + (lane & 15)][kof];
            #pragma unroll
            for (int f = 0; f < 4; ++f) b[f] = *(const half8*)&Bs[wcol + f * 16 + (lane & 15)][kof];
            #pragma unroll
            for (int i = 0; i < 4; ++i)
                #pragma unroll
                for (int j = 0; j < 4; ++j)
                    acc[i][j] = __builtin_amdgcn_mfma_f32_16x16x32_f16(a[i], b[j], acc[i][j], 0, 0, 0);
        }
    }
    #pragma unroll
    for (int i = 0; i < 4; ++i) {
        int row0 = rowBase + wrow + i * 16 + ((lane >> 4) << 2);
        #pragma unroll
        for (int j = 0; j < 4; ++j) {
            int col = colBase + wcol + j * 16 + (lane & 15);
            if (col < NN && row0 < NN) {  // NN%4==0 -> row0<NN implies row0+3<NN
                float sg[4];
                #pragma unroll
                for (int r = 0; r < 4; ++r)
                    sg[r] = __builtin_amdgcn_rcpf(1.0f + __expf(-acc[i][j][r]));
                #pragma unroll
                for (int r = 0; r < 4; ++r)
                    __builtin_nontemporal_store(sg[r], out + (size_t)(row0 + r) * NN + col);
                if (!diag) {
                    f32x4 v = {sg[0], sg[1], sg[2], sg[3]};
                    *(f32x4*)(out + (size_t)col * NN + row0) = v;
                }
            }
        }
    }
}

extern "C" void kernel_launch(void* const* d_in, const int* in_sizes, int n_in,
                              void* d_out, int out_size, void* d_ws, size_t ws_size,
                              hipStream_t stream) {
    const float* features = (const float*)d_in[0];
    const int*   src      = (const int*)d_in[1];
    const int*   dst      = (const int*)d_in[2];
    const float* noise    = (const float*)d_in[3];
    const float* W1 = (const float*)d_in[4];
    const float* b1 = (const float*)d_in[5];
    const float* W2 = (const float*)d_in[6];
    const float* b2 = (const float*)d_in[7];
    const float* W3 = (const float*)d_in[8];
    const float* b3 = (const float*)d_in[9];
    float* out = (float*)d_out;
    (void)in_sizes; (void)n_in; (void)out_size; (void)ws_size;

    char* ws = (char*)d_ws;
    size_t off = 0;
    auto alloc = [&](size_t bytes) -> void* {
        void* p = ws + off;
        off += (bytes + 255) & ~(size_t)255;
        return p;
    };
    int* degc_out = (int*)alloc(NN * sizeof(int));
    int* degc_in  = (int*)alloc(NN * sizeof(int));
    int* row_ptr  = (int*)alloc((NN + 1) * sizeof(int));
    int* cursor   = (int*)alloc(NN * sizeof(int));
    int* esrc     = (int*)alloc(NE * sizeof(int));
    float* rs_out = (float*)alloc(NN * sizeof(float));
    float* rs_in  = (float*)alloc(NN * sizeof(float));
    _Float16* W1Th = (_Float16*)alloc((size_t)H1 * FD * sizeof(_Float16));
    _Float16* W1Tl = (_Float16*)alloc((size_t)H1 * FD * sizeof(_Float16));
    _Float16* WcTh = (_Float16*)alloc((size_t)H1 * H1 * sizeof(_Float16));
    _Float16* WcTl = (_Float16*)alloc((size_t)H1 * H1 * sizeof(_Float16));
    _Float16* y1h  = (_Float16*)alloc((size_t)NN * H1 * sizeof(_Float16));
    _Float16* hh   = (_Float16*)alloc((size_t)NN * H1 * sizeof(_Float16));
    _Float16* hw   = (_Float16*)alloc((size_t)NN * H1 * sizeof(_Float16));
    _Float16* Zh   = (_Float16*)alloc((size_t)NN * H2 * sizeof(_Float16));

    k_zero3<<<(NN + 255) / 256, 256, 0, stream>>>(degc_out, degc_in, cursor, NN);
    k_count<<<(NE + 255) / 256, 256, 0, stream>>>(src, dst, degc_out, degc_in);
    k_scan<<<1, 1024, 0, stream>>>(degc_in, degc_out, row_ptr, rs_in, rs_out);
    k_bucket<<<(NE + 255) / 256, 256, 0, stream>>>(src, dst, row_ptr, cursor, esrc);
    k_castW<<<(FD * H1 + H1 * H1 + 255) / 256, 256, 0, stream>>>(
        W1, W2, W3, W1Th, W1Tl, WcTh, WcTl);

    // y1 = (features * rs_out) @ W1  -> fp16
    k_gemm1<<<dim3((NN + 63) / 64, H1 / 64), 256, 0, stream>>>(
        features, rs_out, W1Th, W1Tl, y1h, NN);
    // h = relu(agg(y1)*rs_in + b1) * rs_out -> fp16
    k_agg<true><<<NN / 4, 256, 0, stream>>>(y1h, hh, esrc, row_ptr, rs_in, rs_out,
                                            b1, nullptr, nullptr, nullptr);
    // hw = h @ [W2|W3] -> fp16
    k_gemm2<<<dim3((NN + 63) / 64, H1 / 64), 256, 0, stream>>>(hh, WcTh, WcTl, hw, NN);
    // Zh = (agg(hw)*rs_in + b2) + noise*exp(agg(hw)*rs_in + b3)  (fused reparam)
    k_agg<false><<<NN / 4, 256, 0, stream>>>(hw, Zh, esrc, row_ptr, rs_in, nullptr,
                                             nullptr, b2, b3, noise);
    // out = sigmoid(Z @ Z^T), symmetric tiles
    const int NB = (NN + 127) / 128;
    k_decoder<<<NB * (NB + 1) / 2, 256, 0, stream>>>(Zh, out);
}